// Round 1
// baseline (1348.222 us; speedup 1.0000x reference)
//
#include <hip/hip_runtime.h>
#include <math.h>

#define BB 8
#define TT 2048
#define CC 1024
#define HH 64
#define NROW (BB*TT)          // 16384
#define NST (NROW*HH)         // 1048576 floats per projection array

// ---------------------------------------------------------------------------
// Kernel 1: complex projections.  ws layout: [kr, ki, qr, qi, vr, vi], each NST.
// grid = (NROW/RT, 3 pairs), block = 128 threads.
// Thread computes 4 rows x 8 h, real+imag (64 accumulators).
// ---------------------------------------------------------------------------
#define RT 64     // rows per block
#define CKK 32    // c-chunk staged in LDS

__global__ __launch_bounds__(128) void proj_kernel(
    const float* __restrict__ xr, const float* __restrict__ xi,
    const float* __restrict__ Wkr, const float* __restrict__ Wki,
    const float* __restrict__ Wqr, const float* __restrict__ Wqi,
    const float* __restrict__ Wvr, const float* __restrict__ Wvi,
    float* __restrict__ ws)
{
    __shared__ float sxr[RT][36];   // stride 36: 16B-aligned rows, 2-way max conflict
    __shared__ float sxi[RT][36];
    __shared__ float swa[CKK][64];
    __shared__ float swb[CKK][64];

    const int tid = threadIdx.x;
    const int p = blockIdx.y;                  // 0=k, 1=q, 2=v
    const long rowbase = (long)blockIdx.x * RT;
    const float* __restrict__ WA = (p == 0) ? Wkr : (p == 1) ? Wqr : Wvr;
    const float* __restrict__ WB = (p == 0) ? Wki : (p == 1) ? Wqi : Wvi;

    const int hg = tid & 7;    // 8 h-groups
    const int rg = tid >> 3;   // 16 row-groups
    const int h0 = hg * 8;
    const int r0 = rg * 4;

    float ar[4][8], ai[4][8];
    #pragma unroll
    for (int r = 0; r < 4; ++r)
        #pragma unroll
        for (int h = 0; h < 8; ++h) { ar[r][h] = 0.f; ai[r][h] = 0.f; }

    for (int c0 = 0; c0 < CC; c0 += CKK) {
        // stage x chunk (RT x CKK, both arrays)
        #pragma unroll
        for (int i = tid; i < RT*CKK; i += 128) {
            int r = i >> 5, cc = i & 31;
            sxr[r][cc] = xr[(rowbase + r)*CC + c0 + cc];
            sxi[r][cc] = xi[(rowbase + r)*CC + c0 + cc];
        }
        // stage W chunk (CKK x 64, both arrays)
        #pragma unroll
        for (int i = tid; i < CKK*64; i += 128) {
            int cc = i >> 6, h = i & 63;
            swa[cc][h] = WA[(c0 + cc)*HH + h];
            swb[cc][h] = WB[(c0 + cc)*HH + h];
        }
        __syncthreads();

        #pragma unroll 1
        for (int cc4 = 0; cc4 < CKK; cc4 += 4) {
            float4 x4r[4], x4i[4];
            #pragma unroll
            for (int r = 0; r < 4; ++r) {
                x4r[r] = *(const float4*)&sxr[r0 + r][cc4];
                x4i[r] = *(const float4*)&sxi[r0 + r][cc4];
            }
            #pragma unroll
            for (int j = 0; j < 4; ++j) {
                float4 wa0 = *(const float4*)&swa[cc4 + j][h0];
                float4 wa1 = *(const float4*)&swa[cc4 + j][h0 + 4];
                float4 wb0 = *(const float4*)&swb[cc4 + j][h0];
                float4 wb1 = *(const float4*)&swb[cc4 + j][h0 + 4];
                float wa[8] = {wa0.x,wa0.y,wa0.z,wa0.w, wa1.x,wa1.y,wa1.z,wa1.w};
                float wb[8] = {wb0.x,wb0.y,wb0.z,wb0.w, wb1.x,wb1.y,wb1.z,wb1.w};
                #pragma unroll
                for (int r = 0; r < 4; ++r) {
                    float xrv = (j==0)?x4r[r].x:(j==1)?x4r[r].y:(j==2)?x4r[r].z:x4r[r].w;
                    float xiv = (j==0)?x4i[r].x:(j==1)?x4i[r].y:(j==2)?x4i[r].z:x4i[r].w;
                    #pragma unroll
                    for (int h = 0; h < 8; ++h) {
                        // out_r = xr@Wr - xi@Wi ; out_i = xi@Wr + xr@Wi
                        ar[r][h] = fmaf(xrv, wa[h], fmaf(-xiv, wb[h], ar[r][h]));
                        ai[r][h] = fmaf(xiv, wa[h], fmaf( xrv, wb[h], ai[r][h]));
                    }
                }
            }
        }
        __syncthreads();
    }

    float* outr = ws + (size_t)(2*p)     * NST;
    float* outi = ws + (size_t)(2*p + 1) * NST;
    #pragma unroll
    for (int r = 0; r < 4; ++r) {
        size_t o = (size_t)(rowbase + r0 + r) * HH + h0;
        *(float4*)&outr[o]     = make_float4(ar[r][0],ar[r][1],ar[r][2],ar[r][3]);
        *(float4*)&outr[o + 4] = make_float4(ar[r][4],ar[r][5],ar[r][6],ar[r][7]);
        *(float4*)&outi[o]     = make_float4(ai[r][0],ai[r][1],ai[r][2],ai[r][3]);
        *(float4*)&outi[o + 4] = make_float4(ai[r][4],ai[r][5],ai[r][6],ai[r][7]);
    }
}

// ---------------------------------------------------------------------------
// Kernel 2: flash-style complex attention.
// grid = (T/32 q-tiles, B), block = 256 threads. k-tiles of 32, online softmax.
// ---------------------------------------------------------------------------
__global__ __launch_bounds__(256) void attn_kernel(
    const float* __restrict__ kr, const float* __restrict__ ki,
    const float* __restrict__ qr, const float* __restrict__ qi,
    const float* __restrict__ vr, const float* __restrict__ vi,
    float* __restrict__ out)
{
    __shared__ float2 sq[32*65];   // (qr,qi) interleaved, row stride 65
    __shared__ float2 sk[32*65];
    __shared__ float2 sv[32*64];
    __shared__ float  sp[32*36];   // score/prob tile, row stride 36 (16B aligned)
    __shared__ float  sm[32], sl[32], sal[32];

    const int tid = threadIdx.x;
    const int qt = blockIdx.x, b = blockIdx.y;
    const size_t qbase = ((size_t)b*TT + (size_t)qt*32) * HH;

    for (int i = tid; i < 32*64; i += 256) {
        int r = i >> 6, h = i & 63;
        sq[r*65 + h] = make_float2(qr[qbase + i], qi[qbase + i]);
    }
    if (tid < 32) { sm[tid] = -INFINITY; sl[tid] = 0.f; }

    float Or[8], Oi[8];
    #pragma unroll
    for (int s = 0; s < 8; ++s) { Or[s] = 0.f; Oi[s] = 0.f; }

    const int tx = tid & 15, ty = tid >> 4;   // S-role: 2x2 tile at (2ty, 2tx)
    const int kj0 = 2*tx, qi0 = 2*ty;
    const int hh = tid & 63, qg = tid >> 6;   // PV-role: h=hh, rows qg+4s

    __syncthreads();

    for (int kt = 0; kt <= qt; ++kt) {
        const size_t kbase = ((size_t)b*TT + (size_t)kt*32) * HH;
        for (int i = tid; i < 32*64; i += 256) {
            int r = i >> 6, h = i & 63;
            sk[r*65 + h] = make_float2(kr[kbase + i], ki[kbase + i]);
            sv[r*64 + h] = make_float2(vr[kbase + i], vi[kbase + i]);
        }
        __syncthreads();

        // ---- S = complex scores, 2x2 per thread ----
        float wr[2][2] = {{0.f,0.f},{0.f,0.f}};
        float wi[2][2] = {{0.f,0.f},{0.f,0.f}};
        #pragma unroll 4
        for (int h = 0; h < HH; ++h) {
            float2 qa = sq[qi0*65 + h];
            float2 qb = sq[(qi0+1)*65 + h];
            float2 ka = sk[kj0*65 + h];
            float2 kb = sk[(kj0+1)*65 + h];
            // wei_r = qr.kr + qi.ki ; wei_i = qi.kr - qr.ki
            wr[0][0] = fmaf(qa.x, ka.x, fmaf(qa.y, ka.y, wr[0][0]));
            wi[0][0] = fmaf(qa.y, ka.x, fmaf(-qa.x, ka.y, wi[0][0]));
            wr[0][1] = fmaf(qa.x, kb.x, fmaf(qa.y, kb.y, wr[0][1]));
            wi[0][1] = fmaf(qa.y, kb.x, fmaf(-qa.x, kb.y, wi[0][1]));
            wr[1][0] = fmaf(qb.x, ka.x, fmaf(qb.y, ka.y, wr[1][0]));
            wi[1][0] = fmaf(qb.y, ka.x, fmaf(-qb.x, ka.y, wi[1][0]));
            wr[1][1] = fmaf(qb.x, kb.x, fmaf(qb.y, kb.y, wr[1][1]));
            wi[1][1] = fmaf(qb.y, kb.x, fmaf(-qb.x, kb.y, wi[1][1]));
        }
        #pragma unroll
        for (int dq = 0; dq < 2; ++dq)
            #pragma unroll
            for (int dk = 0; dk < 2; ++dk) {
                float m = sqrtf(fmaf(wr[dq][dk], wr[dq][dk],
                                fmaf(wi[dq][dk], wi[dq][dk], 1e-4f))) * 0.125f;
                if (kt == qt && (kj0 + dk) > (qi0 + dq)) m = -INFINITY;
                sp[(qi0 + dq)*36 + kj0 + dk] = m;
            }
        __syncthreads();

        // ---- online softmax row stats ----
        if (tid < 32) {
            float mold = sm[tid], mnew = mold;
            #pragma unroll
            for (int k = 0; k < 32; ++k) mnew = fmaxf(mnew, sp[tid*36 + k]);
            float alpha = __expf(mold - mnew);
            float ssum = 0.f;
            #pragma unroll
            for (int k = 0; k < 32; ++k) {
                float pv = __expf(sp[tid*36 + k] - mnew);
                sp[tid*36 + k] = pv;
                ssum += pv;
            }
            sm[tid] = mnew;
            sl[tid] = fmaf(sl[tid], alpha, ssum);
            sal[tid] = alpha;
        }
        __syncthreads();

        // ---- PV accumulate ----
        #pragma unroll
        for (int s = 0; s < 8; ++s) {
            float a = sal[qg + 4*s];
            Or[s] *= a; Oi[s] *= a;
        }
        #pragma unroll 1
        for (int k4 = 0; k4 < 32; k4 += 4) {
            float2 va = sv[(k4+0)*64 + hh];
            float2 vb = sv[(k4+1)*64 + hh];
            float2 vc = sv[(k4+2)*64 + hh];
            float2 vd = sv[(k4+3)*64 + hh];
            #pragma unroll
            for (int s = 0; s < 8; ++s) {
                float4 p4 = *(const float4*)&sp[(qg + 4*s)*36 + k4];
                Or[s] = fmaf(p4.x, va.x, Or[s]); Oi[s] = fmaf(p4.x, va.y, Oi[s]);
                Or[s] = fmaf(p4.y, vb.x, Or[s]); Oi[s] = fmaf(p4.y, vb.y, Oi[s]);
                Or[s] = fmaf(p4.z, vc.x, Or[s]); Oi[s] = fmaf(p4.z, vc.y, Oi[s]);
                Or[s] = fmaf(p4.w, vd.x, Or[s]); Oi[s] = fmaf(p4.w, vd.y, Oi[s]);
            }
        }
        __syncthreads();
    }

    #pragma unroll
    for (int s = 0; s < 8; ++s) {
        int qrow = qg + 4*s;
        float inv = 1.0f / sl[qrow];
        size_t o = qbase + (size_t)qrow*HH + hh;
        out[o]       = Or[s] * inv;
        out[NST + o] = Oi[s] * inv;
    }
}

extern "C" void kernel_launch(void* const* d_in, const int* in_sizes, int n_in,
                              void* d_out, int out_size, void* d_ws, size_t ws_size,
                              hipStream_t stream)
{
    const float* xr  = (const float*)d_in[0];
    const float* xi  = (const float*)d_in[1];
    const float* Wkr = (const float*)d_in[2];
    const float* Wki = (const float*)d_in[3];
    const float* Wqr = (const float*)d_in[4];
    const float* Wqi = (const float*)d_in[5];
    const float* Wvr = (const float*)d_in[6];
    const float* Wvi = (const float*)d_in[7];
    float* ws  = (float*)d_ws;
    float* out = (float*)d_out;

    dim3 g1(NROW/RT, 3);
    proj_kernel<<<g1, 128, 0, stream>>>(xr, xi, Wkr, Wki, Wqr, Wqi, Wvr, Wvi, ws);

    const float* pkr = ws + 0*(size_t)NST;
    const float* pki = ws + 1*(size_t)NST;
    const float* pqr = ws + 2*(size_t)NST;
    const float* pqi = ws + 3*(size_t)NST;
    const float* pvr = ws + 4*(size_t)NST;
    const float* pvi = ws + 5*(size_t)NST;

    dim3 g2(TT/32, BB);
    attn_kernel<<<g2, 256, 0, stream>>>(pkr, pki, pqr, pqi, pvr, pvi, out);
}

// Round 2
// 739.556 us; speedup vs baseline: 1.8230x; 1.8230x over previous
//
#include <hip/hip_runtime.h>
#include <hip/hip_bf16.h>
#include <math.h>

#define BB 8
#define TT 2048
#define CC 1024
#define HH 64
#define NROW (BB*TT)          // 16384
#define NST (NROW*HH)         // 1048576 floats per projection array
#define KK2 2048              // combined K = 2C
#define NN 384                // combined N = 6*64

typedef __attribute__((ext_vector_type(8))) short short8;
typedef __attribute__((ext_vector_type(4))) float f32x4;

static __device__ inline unsigned pk_bf16(float a, float b) {
    __hip_bfloat162 h = __float22bfloat162_rn(make_float2(a, b));
    unsigned u; __builtin_memcpy(&u, &h, 4); return u;
}
static __device__ inline short f2bf_s(float a) {
    __hip_bfloat16 h = __float2bfloat16(a);
    short s; __builtin_memcpy(&s, &h, 2); return s;
}

// ---------------------------------------------------------------------------
// Kernel 0: build Bt[n][k] bf16, n = 64*g + h, g in [kr,ki,qr,qi,vr,vi].
//   real cols (g even): [Wr ; -Wi] ; imag cols (g odd): [Wi ; Wr]
// grid = NN blocks, 256 threads; thread j handles k = tid + 256*j.
// ---------------------------------------------------------------------------
__global__ __launch_bounds__(256) void prep_kernel(
    const float* __restrict__ Wkr, const float* __restrict__ Wki,
    const float* __restrict__ Wqr, const float* __restrict__ Wqi,
    const float* __restrict__ Wvr, const float* __restrict__ Wvi,
    short* __restrict__ Bt)
{
    const int n = blockIdx.x;
    const int g = n >> 6, h = n & 63;
    const int p = g >> 1;
    const bool im = g & 1;
    const float* Wr = (p == 0) ? Wkr : (p == 1) ? Wqr : Wvr;
    const float* Wi = (p == 0) ? Wki : (p == 1) ? Wqi : Wvi;
    const float* W1 = im ? Wi : Wr;      // k < 1024
    const float* W2 = im ? Wr : Wi;      // k >= 1024
    const float s2 = im ? 1.f : -1.f;

    #pragma unroll
    for (int j = 0; j < 8; ++j) {
        int k = threadIdx.x + 256 * j;
        float v = (k < CC) ? W1[k * HH + h] : s2 * W2[(k - CC) * HH + h];
        Bt[(size_t)n * KK2 + k] = f2bf_s(v);
    }
}

// ---------------------------------------------------------------------------
// Kernel 1: bf16 MFMA GEMM  [xr|xi](16384x2048) @ Bt^T(2048x384) -> 6 fp32 arrays.
// BM=128 BN=128 BK=64, 256 threads = 4 waves (2x2), wave tile 64x64,
// mfma_f32_16x16x32_bf16, LDS rows padded to 72 bf16.
// ---------------------------------------------------------------------------
#define BK 64
#define LDP 72   // padded LDS row stride in bf16

__global__ __launch_bounds__(256) void proj_gemm(
    const float* __restrict__ xr, const float* __restrict__ xi,
    const short* __restrict__ Bt,
    float* __restrict__ out)   // 6 * NST floats: [kr,ki,qr,qi,vr,vi]
{
    __shared__ __attribute__((aligned(16))) short sA[128 * LDP];
    __shared__ __attribute__((aligned(16))) short sB[128 * LDP];

    const int tid = threadIdx.x;
    const int mbase = blockIdx.x * 128;
    const int n0 = blockIdx.y * 128;

    const int wave = tid >> 6, lane = tid & 63;
    const int wr = wave >> 1, wc = wave & 1;
    const int quad = lane >> 4, lm = lane & 15;

    f32x4 acc[4][4] = {};

    for (int ks = 0; ks < KK2 / BK; ++ks) {
        // ---- global loads into registers ----
        const float* __restrict__ srcA = (ks < 16) ? xr : xi;
        const int kc = (ks & 15) * BK;
        float4 av[8];
        #pragma unroll
        for (int j = 0; j < 8; ++j) {
            int id = tid + 256 * j;
            int r = id >> 4, c4 = id & 15;
            av[j] = *(const float4*)&srcA[(size_t)(mbase + r) * CC + kc + c4 * 4];
        }
        uint4 bv[4];
        #pragma unroll
        for (int j = 0; j < 4; ++j) {
            int id = tid + 256 * j;
            int nn = id >> 3, c8 = id & 7;
            bv[j] = *(const uint4*)&Bt[(size_t)(n0 + nn) * KK2 + ks * BK + c8 * 8];
        }
        __syncthreads();   // prev iter's frag reads done before overwrite

        // ---- cvt + LDS writes ----
        #pragma unroll
        for (int j = 0; j < 8; ++j) {
            int id = tid + 256 * j;
            int r = id >> 4, c4 = id & 15;
            uint2 pkd;
            pkd.x = pk_bf16(av[j].x, av[j].y);
            pkd.y = pk_bf16(av[j].z, av[j].w);
            *(uint2*)&sA[r * LDP + c4 * 4] = pkd;
        }
        #pragma unroll
        for (int j = 0; j < 4; ++j) {
            int id = tid + 256 * j;
            int nn = id >> 3, c8 = id & 7;
            *(uint4*)&sB[nn * LDP + c8 * 8] = bv[j];
        }
        __syncthreads();

        // ---- fragments + MFMA ----
        #pragma unroll
        for (int kk = 0; kk < 2; ++kk) {
            short8 af[4], bf[4];
            #pragma unroll
            for (int mi = 0; mi < 4; ++mi)
                af[mi] = *(const short8*)&sA[(64*wr + 16*mi + lm) * LDP + kk*32 + quad*8];
            #pragma unroll
            for (int ni = 0; ni < 4; ++ni)
                bf[ni] = *(const short8*)&sB[(64*wc + 16*ni + lm) * LDP + kk*32 + quad*8];
            #pragma unroll
            for (int mi = 0; mi < 4; ++mi)
                #pragma unroll
                for (int ni = 0; ni < 4; ++ni)
                    acc[mi][ni] = __builtin_amdgcn_mfma_f32_16x16x32_bf16(
                        af[mi], bf[ni], acc[mi][ni], 0, 0, 0);
        }
    }

    // ---- epilogue: D row = quad*4+reg, col = lm ----
    const int g = 2 * blockIdx.y + wc;          // output array index (uniform/wave)
    float* __restrict__ og = out + (size_t)g * NST;
    #pragma unroll
    for (int mi = 0; mi < 4; ++mi) {
        #pragma unroll
        for (int ni = 0; ni < 4; ++ni) {
            #pragma unroll
            for (int r = 0; r < 4; ++r) {
                int row = mbase + 64*wr + 16*mi + quad*4 + r;
                og[(size_t)row * HH + 16*ni + lm] = acc[mi][ni][r];
            }
        }
    }
}

// ---------------------------------------------------------------------------
// Kernel 2: flash-style complex attention (unchanged from round 1).
// ---------------------------------------------------------------------------
__global__ __launch_bounds__(256) void attn_kernel(
    const float* __restrict__ kr, const float* __restrict__ ki,
    const float* __restrict__ qr, const float* __restrict__ qi,
    const float* __restrict__ vr, const float* __restrict__ vi,
    float* __restrict__ out)
{
    __shared__ float2 sq[32*65];
    __shared__ float2 sk[32*65];
    __shared__ float2 sv[32*64];
    __shared__ float  sp[32*36];
    __shared__ float  sm[32], sl[32], sal[32];

    const int tid = threadIdx.x;
    const int qt = blockIdx.x, b = blockIdx.y;
    const size_t qbase = ((size_t)b*TT + (size_t)qt*32) * HH;

    for (int i = tid; i < 32*64; i += 256) {
        int r = i >> 6, h = i & 63;
        sq[r*65 + h] = make_float2(qr[qbase + i], qi[qbase + i]);
    }
    if (tid < 32) { sm[tid] = -INFINITY; sl[tid] = 0.f; }

    float Or[8], Oi[8];
    #pragma unroll
    for (int s = 0; s < 8; ++s) { Or[s] = 0.f; Oi[s] = 0.f; }

    const int tx = tid & 15, ty = tid >> 4;
    const int kj0 = 2*tx, qi0 = 2*ty;
    const int hh = tid & 63, qg = tid >> 6;

    __syncthreads();

    for (int kt = 0; kt <= qt; ++kt) {
        const size_t kbase = ((size_t)b*TT + (size_t)kt*32) * HH;
        for (int i = tid; i < 32*64; i += 256) {
            int r = i >> 6, h = i & 63;
            sk[r*65 + h] = make_float2(kr[kbase + i], ki[kbase + i]);
            sv[r*64 + h] = make_float2(vr[kbase + i], vi[kbase + i]);
        }
        __syncthreads();

        float wr2[2][2] = {{0.f,0.f},{0.f,0.f}};
        float wi2[2][2] = {{0.f,0.f},{0.f,0.f}};
        #pragma unroll 4
        for (int h = 0; h < HH; ++h) {
            float2 qa = sq[qi0*65 + h];
            float2 qb = sq[(qi0+1)*65 + h];
            float2 ka = sk[kj0*65 + h];
            float2 kb = sk[(kj0+1)*65 + h];
            wr2[0][0] = fmaf(qa.x, ka.x, fmaf(qa.y, ka.y, wr2[0][0]));
            wi2[0][0] = fmaf(qa.y, ka.x, fmaf(-qa.x, ka.y, wi2[0][0]));
            wr2[0][1] = fmaf(qa.x, kb.x, fmaf(qa.y, kb.y, wr2[0][1]));
            wi2[0][1] = fmaf(qa.y, kb.x, fmaf(-qa.x, kb.y, wi2[0][1]));
            wr2[1][0] = fmaf(qb.x, ka.x, fmaf(qb.y, ka.y, wr2[1][0]));
            wi2[1][0] = fmaf(qb.y, ka.x, fmaf(-qb.x, ka.y, wi2[1][0]));
            wr2[1][1] = fmaf(qb.x, kb.x, fmaf(qb.y, kb.y, wr2[1][1]));
            wi2[1][1] = fmaf(qb.y, kb.x, fmaf(-qb.x, kb.y, wi2[1][1]));
        }
        #pragma unroll
        for (int dq = 0; dq < 2; ++dq)
            #pragma unroll
            for (int dk = 0; dk < 2; ++dk) {
                float m = sqrtf(fmaf(wr2[dq][dk], wr2[dq][dk],
                                fmaf(wi2[dq][dk], wi2[dq][dk], 1e-4f))) * 0.125f;
                if (kt == qt && (kj0 + dk) > (qi0 + dq)) m = -INFINITY;
                sp[(qi0 + dq)*36 + kj0 + dk] = m;
            }
        __syncthreads();

        if (tid < 32) {
            float mold = sm[tid], mnew = mold;
            #pragma unroll
            for (int k = 0; k < 32; ++k) mnew = fmaxf(mnew, sp[tid*36 + k]);
            float alpha = __expf(mold - mnew);
            float ssum = 0.f;
            #pragma unroll
            for (int k = 0; k < 32; ++k) {
                float pv = __expf(sp[tid*36 + k] - mnew);
                sp[tid*36 + k] = pv;
                ssum += pv;
            }
            sm[tid] = mnew;
            sl[tid] = fmaf(sl[tid], alpha, ssum);
            sal[tid] = alpha;
        }
        __syncthreads();

        #pragma unroll
        for (int s = 0; s < 8; ++s) {
            float a = sal[qg + 4*s];
            Or[s] *= a; Oi[s] *= a;
        }
        #pragma unroll 1
        for (int k4 = 0; k4 < 32; k4 += 4) {
            float2 va = sv[(k4+0)*64 + hh];
            float2 vb = sv[(k4+1)*64 + hh];
            float2 vc = sv[(k4+2)*64 + hh];
            float2 vd = sv[(k4+3)*64 + hh];
            #pragma unroll
            for (int s = 0; s < 8; ++s) {
                float4 p4 = *(const float4*)&sp[(qg + 4*s)*36 + k4];
                Or[s] = fmaf(p4.x, va.x, Or[s]); Oi[s] = fmaf(p4.x, va.y, Oi[s]);
                Or[s] = fmaf(p4.y, vb.x, Or[s]); Oi[s] = fmaf(p4.y, vb.y, Oi[s]);
                Or[s] = fmaf(p4.z, vc.x, Or[s]); Oi[s] = fmaf(p4.z, vc.y, Oi[s]);
                Or[s] = fmaf(p4.w, vd.x, Or[s]); Oi[s] = fmaf(p4.w, vd.y, Oi[s]);
            }
        }
        __syncthreads();
    }

    #pragma unroll
    for (int s = 0; s < 8; ++s) {
        int qrow = qg + 4*s;
        float inv = 1.0f / sl[qrow];
        size_t o = qbase + (size_t)qrow*HH + hh;
        out[o]       = Or[s] * inv;
        out[NST + o] = Oi[s] * inv;
    }
}

extern "C" void kernel_launch(void* const* d_in, const int* in_sizes, int n_in,
                              void* d_out, int out_size, void* d_ws, size_t ws_size,
                              hipStream_t stream)
{
    const float* xr  = (const float*)d_in[0];
    const float* xi  = (const float*)d_in[1];
    const float* Wkr = (const float*)d_in[2];
    const float* Wki = (const float*)d_in[3];
    const float* Wqr = (const float*)d_in[4];
    const float* Wqi = (const float*)d_in[5];
    const float* Wvr = (const float*)d_in[6];
    const float* Wvi = (const float*)d_in[7];

    short* Bt    = (short*)d_ws;                              // 1.5 MB
    float* projo = (float*)((char*)d_ws + (2u << 20));        // 24 MB, [kr,ki,qr,qi,vr,vi]
    float* out   = (float*)d_out;

    prep_kernel<<<NN, 256, 0, stream>>>(Wkr, Wki, Wqr, Wqi, Wvr, Wvi, Bt);

    dim3 g1(NROW / 128, NN / 128);
    proj_gemm<<<g1, 256, 0, stream>>>(xr, xi, Bt, projo);

    const float* pkr = projo + 0*(size_t)NST;
    const float* pki = projo + 1*(size_t)NST;
    const float* pqr = projo + 2*(size_t)NST;
    const float* pqi = projo + 3*(size_t)NST;
    const float* pvr = projo + 4*(size_t)NST;
    const float* pvi = projo + 5*(size_t)NST;

    dim3 g2(TT/32, BB);
    attn_kernel<<<g2, 256, 0, stream>>>(pkr, pki, pqr, pqi, pvr, pvi, out);
}

// Round 3
// 338.983 us; speedup vs baseline: 3.9773x; 2.1817x over previous
//
#include <hip/hip_runtime.h>
#include <hip/hip_bf16.h>
#include <math.h>

#define BB 8
#define TT 2048
#define CC 1024
#define HH 64
#define NROW (BB*TT)          // 16384
#define NST (NROW*HH)         // 1048576 elements per output component
#define KK2 2048              // combined GEMM K = 2C
#define NN 384                // combined GEMM N = 6*64

typedef __attribute__((ext_vector_type(8))) short short8;
typedef __attribute__((ext_vector_type(4))) float f32x4;

static __device__ inline unsigned pk_bf16(float a, float b) {
    __hip_bfloat162 h = __float22bfloat162_rn(make_float2(a, b));
    unsigned u; __builtin_memcpy(&u, &h, 4); return u;
}
static __device__ inline short f2bf_s(float a) {
    __hip_bfloat16 h = __float2bfloat16(a);
    short s; __builtin_memcpy(&s, &h, 2); return s;
}
static __device__ inline short8 neg8(short8 a) {
    short8 r;
    #pragma unroll
    for (int i = 0; i < 8; ++i) r[i] = a[i] ^ (short)0x8000;
    return r;
}

// ---------------------------------------------------------------------------
// Kernel 0: build Bt[n][k] bf16 for the projection GEMM.
// n = 64*g + h, g in [kr,ki,qr,qi,vr,vi]; real: [Wr;-Wi], imag: [Wi;Wr].
// ---------------------------------------------------------------------------
__global__ __launch_bounds__(256) void prep_kernel(
    const float* __restrict__ Wkr, const float* __restrict__ Wki,
    const float* __restrict__ Wqr, const float* __restrict__ Wqi,
    const float* __restrict__ Wvr, const float* __restrict__ Wvi,
    short* __restrict__ Bt)
{
    const int n = blockIdx.x;
    const int g = n >> 6, h = n & 63;
    const int p = g >> 1;
    const bool im = g & 1;
    const float* Wr = (p == 0) ? Wkr : (p == 1) ? Wqr : Wvr;
    const float* Wi = (p == 0) ? Wki : (p == 1) ? Wqi : Wvi;
    const float* W1 = im ? Wi : Wr;
    const float* W2 = im ? Wr : Wi;
    const float s2 = im ? 1.f : -1.f;

    #pragma unroll
    for (int j = 0; j < 8; ++j) {
        int k = threadIdx.x + 256 * j;
        float v = (k < CC) ? W1[k * HH + h] : s2 * W2[(k - CC) * HH + h];
        Bt[(size_t)n * KK2 + k] = f2bf_s(v);
    }
}

// ---------------------------------------------------------------------------
// Kernel 1: bf16 MFMA GEMM -> G[16384][384] bf16 (token-major, cols =
// [kr0..63 | ki | qr | qi | vr | vi]).
// ---------------------------------------------------------------------------
#define BK 64
#define LDP 72

__global__ __launch_bounds__(256) void proj_gemm(
    const float* __restrict__ xr, const float* __restrict__ xi,
    const short* __restrict__ Bt,
    short* __restrict__ G)
{
    __shared__ __attribute__((aligned(16))) short sA[128 * LDP];
    __shared__ __attribute__((aligned(16))) short sB[128 * LDP];

    const int tid = threadIdx.x;
    const int mbase = blockIdx.x * 128;
    const int n0 = blockIdx.y * 128;

    const int wave = tid >> 6, lane = tid & 63;
    const int wr = wave >> 1, wc = wave & 1;
    const int quad = lane >> 4, lm = lane & 15;

    f32x4 acc[4][4] = {};

    for (int ks = 0; ks < KK2 / BK; ++ks) {
        const float* __restrict__ srcA = (ks < 16) ? xr : xi;
        const int kc = (ks & 15) * BK;
        float4 av[8];
        #pragma unroll
        for (int j = 0; j < 8; ++j) {
            int id = tid + 256 * j;
            int r = id >> 4, c4 = id & 15;
            av[j] = *(const float4*)&srcA[(size_t)(mbase + r) * CC + kc + c4 * 4];
        }
        uint4 bv[4];
        #pragma unroll
        for (int j = 0; j < 4; ++j) {
            int id = tid + 256 * j;
            int nn = id >> 3, c8 = id & 7;
            bv[j] = *(const uint4*)&Bt[(size_t)(n0 + nn) * KK2 + ks * BK + c8 * 8];
        }
        __syncthreads();

        #pragma unroll
        for (int j = 0; j < 8; ++j) {
            int id = tid + 256 * j;
            int r = id >> 4, c4 = id & 15;
            uint2 pkd;
            pkd.x = pk_bf16(av[j].x, av[j].y);
            pkd.y = pk_bf16(av[j].z, av[j].w);
            *(uint2*)&sA[r * LDP + c4 * 4] = pkd;
        }
        #pragma unroll
        for (int j = 0; j < 4; ++j) {
            int id = tid + 256 * j;
            int nn = id >> 3, c8 = id & 7;
            *(uint4*)&sB[nn * LDP + c8 * 8] = bv[j];
        }
        __syncthreads();

        #pragma unroll
        for (int kk = 0; kk < 2; ++kk) {
            short8 af[4], bf[4];
            #pragma unroll
            for (int mi = 0; mi < 4; ++mi)
                af[mi] = *(const short8*)&sA[(64*wr + 16*mi + lm) * LDP + kk*32 + quad*8];
            #pragma unroll
            for (int ni = 0; ni < 4; ++ni)
                bf[ni] = *(const short8*)&sB[(64*wc + 16*ni + lm) * LDP + kk*32 + quad*8];
            #pragma unroll
            for (int mi = 0; mi < 4; ++mi)
                #pragma unroll
                for (int ni = 0; ni < 4; ++ni)
                    acc[mi][ni] = __builtin_amdgcn_mfma_f32_16x16x32_bf16(
                        af[mi], bf[ni], acc[mi][ni], 0, 0, 0);
        }
    }

    const int g = 2 * blockIdx.y + wc;   // 0..5 -> [kr,ki,qr,qi,vr,vi]
    #pragma unroll
    for (int mi = 0; mi < 4; ++mi)
        #pragma unroll
        for (int ni = 0; ni < 4; ++ni)
            #pragma unroll
            for (int r = 0; r < 4; ++r) {
                int row = mbase + 64*wr + 16*mi + quad*4 + r;
                G[(size_t)row * NN + g*64 + 16*ni + lm] = f2bf_s(acc[mi][ni][r]);
            }
}

// ---------------------------------------------------------------------------
// Kernel 2: transpose V to h-major: VT[comp][b][h][t] bf16.
// grid (8 b, 128 hc), 256 threads, 8 tokens/thread.
// ---------------------------------------------------------------------------
__global__ __launch_bounds__(256) void vtrans_kernel(
    const short* __restrict__ G, short* __restrict__ VT)
{
    const int b = blockIdx.x, hc = blockIdx.y;
    const int t0 = threadIdx.x * 8;
    short8 v;
    #pragma unroll
    for (int i = 0; i < 8; ++i)
        v[i] = G[((size_t)b*TT + t0 + i) * NN + 256 + hc];
    size_t o = (((size_t)(hc >> 6) * BB + b) * 64 + (hc & 63)) * TT + t0;
    *(short8*)(VT + o) = v;
}

// ---------------------------------------------------------------------------
// Kernel 3: MFMA flash attention. Wave-autonomous 16-row q-tiles; 4 waves/block
// split the k-range (kt % 4 == wave) and merge (m,l,O) via LDS at the end.
// grid = (128 q-tiles, 8 b), 256 threads.
// ---------------------------------------------------------------------------
#define PLDS 72

__global__ __launch_bounds__(256) void attn_kernel(
    const short* __restrict__ G,
    const short* __restrict__ VT,
    float* __restrict__ out)
{
    __shared__ float comb[4][16][128];
    __shared__ float cmw[4][16], clw[4][16];

    const int tid = threadIdx.x;
    const int wave = tid >> 6, lane = tid & 63;
    const int quad = lane >> 4, lm = lane & 15;
    const int j = blockIdx.x, b = blockIdx.y;
    const int qbase = j * 16;
    const int nkt = (j >> 2) + 1;    // k-tiles of 64 tokens

    // Q fragments: A1 = [Qr|Qi], A2 = [Qi|-Qr]  (k = 0..127)
    const short* Qrow = G + ((size_t)(b*TT + qbase + lm)) * NN + 128;
    short8 A1[4], A2[4];
    #pragma unroll
    for (int ks = 0; ks < 4; ++ks)
        A1[ks] = *(const short8*)(Qrow + ks*32 + quad*8);
    A2[0] = A1[2]; A2[1] = A1[3];
    A2[2] = neg8(A1[0]); A2[3] = neg8(A1[1]);

    f32x4 Or[4] = {{0.f,0.f,0.f,0.f}}, Oi[4] = {{0.f,0.f,0.f,0.f}};
    #pragma unroll
    for (int h = 0; h < 4; ++h)
        #pragma unroll
        for (int r = 0; r < 4; ++r) { Or[h][r] = 0.f; Oi[h][r] = 0.f; }
    float m[4], l[4];
    #pragma unroll
    for (int r = 0; r < 4; ++r) { m[r] = -INFINITY; l[r] = 0.f; }

    short* Pw = (short*)&comb[wave][0][0];          // per-wave 16 x PLDS scratch
    const short* Vrb = VT + (size_t)b * 64 * TT;
    const short* Vib = Vrb + (size_t)BB * 64 * TT;

    for (int kt = wave; kt < nkt; kt += 4) {
        const int kb = kt * 64;
        const short* Kt = G + ((size_t)(b*TT + kb)) * NN;

        f32x4 mag[4];
        #pragma unroll
        for (int nt = 0; nt < 4; ++nt) {
            const short* Krow = Kt + (size_t)(nt*16 + lm) * NN;
            short8 Bf[4];
            #pragma unroll
            for (int ks = 0; ks < 4; ++ks)
                Bf[ks] = *(const short8*)(Krow + ks*32 + quad*8);
            f32x4 sr = {0.f,0.f,0.f,0.f}, si = {0.f,0.f,0.f,0.f};
            #pragma unroll
            for (int ks = 0; ks < 4; ++ks) {
                sr = __builtin_amdgcn_mfma_f32_16x16x32_bf16(A1[ks], Bf[ks], sr, 0,0,0);
                si = __builtin_amdgcn_mfma_f32_16x16x32_bf16(A2[ks], Bf[ks], si, 0,0,0);
            }
            int tok = kb + nt*16 + lm;
            #pragma unroll
            for (int r = 0; r < 4; ++r) {
                float v = sqrtf(fmaf(sr[r], sr[r], fmaf(si[r], si[r], 1e-4f))) * 0.125f;
                int qrow = qbase + quad*4 + r;
                mag[nt][r] = (tok > qrow) ? -INFINITY : v;
            }
        }

        // row max across 4 n-tiles and 16 lanes
        float tm[4];
        #pragma unroll
        for (int r = 0; r < 4; ++r)
            tm[r] = fmaxf(fmaxf(mag[0][r], mag[1][r]), fmaxf(mag[2][r], mag[3][r]));
        #pragma unroll
        for (int d = 1; d < 16; d <<= 1)
            #pragma unroll
            for (int r = 0; r < 4; ++r)
                tm[r] = fmaxf(tm[r], __shfl_xor(tm[r], d, 16));

        float al[4], ps[4];
        #pragma unroll
        for (int r = 0; r < 4; ++r) {
            float mn = fmaxf(m[r], tm[r]);
            al[r] = __expf(m[r] - mn);
            m[r] = mn;
            ps[r] = 0.f;
        }
        #pragma unroll
        for (int nt = 0; nt < 4; ++nt)
            #pragma unroll
            for (int r = 0; r < 4; ++r) {
                float p = __expf(mag[nt][r] - m[r]);
                mag[nt][r] = p;
                ps[r] += p;
            }
        #pragma unroll
        for (int d = 1; d < 16; d <<= 1)
            #pragma unroll
            for (int r = 0; r < 4; ++r)
                ps[r] += __shfl_xor(ps[r], d, 16);
        #pragma unroll
        for (int r = 0; r < 4; ++r)
            l[r] = fmaf(l[r], al[r], ps[r]);

        #pragma unroll
        for (int h = 0; h < 4; ++h)
            #pragma unroll
            for (int r = 0; r < 4; ++r) { Or[h][r] *= al[r]; Oi[h][r] *= al[r]; }

        // P (C-layout) -> LDS -> A-frags  (wave-internal, no barrier)
        #pragma unroll
        for (int nt = 0; nt < 4; ++nt)
            #pragma unroll
            for (int r = 0; r < 4; ++r)
                Pw[(quad*4 + r) * PLDS + nt*16 + lm] = f2bf_s(mag[nt][r]);
        short8 Af0 = *(const short8*)&Pw[lm * PLDS + quad*8];
        short8 Af1 = *(const short8*)&Pw[lm * PLDS + 32 + quad*8];

        // PV
        #pragma unroll
        for (int ht = 0; ht < 4; ++ht) {
            const short* vr0 = Vrb + (size_t)(ht*16 + lm) * TT + kb + quad*8;
            const short* vi0 = Vib + (size_t)(ht*16 + lm) * TT + kb + quad*8;
            short8 br0 = *(const short8*)(vr0);
            short8 br1 = *(const short8*)(vr0 + 32);
            short8 bi0 = *(const short8*)(vi0);
            short8 bi1 = *(const short8*)(vi0 + 32);
            Or[ht] = __builtin_amdgcn_mfma_f32_16x16x32_bf16(Af0, br0, Or[ht], 0,0,0);
            Or[ht] = __builtin_amdgcn_mfma_f32_16x16x32_bf16(Af1, br1, Or[ht], 0,0,0);
            Oi[ht] = __builtin_amdgcn_mfma_f32_16x16x32_bf16(Af0, bi0, Oi[ht], 0,0,0);
            Oi[ht] = __builtin_amdgcn_mfma_f32_16x16x32_bf16(Af1, bi1, Oi[ht], 0,0,0);
        }
    }

    __syncthreads();   // all waves done with their Pw region

    #pragma unroll
    for (int ht = 0; ht < 4; ++ht)
        #pragma unroll
        for (int r = 0; r < 4; ++r) {
            comb[wave][quad*4 + r][ht*16 + lm]      = Or[ht][r];
            comb[wave][quad*4 + r][64 + ht*16 + lm] = Oi[ht][r];
        }
    if (lm == 0) {
        #pragma unroll
        for (int r = 0; r < 4; ++r) {
            cmw[wave][quad*4 + r] = m[r];
            clw[wave][quad*4 + r] = l[r];
        }
    }
    __syncthreads();

    for (int e = tid; e < 16*128; e += 256) {
        int q = e >> 7, h = e & 127;
        float mstar = fmaxf(fmaxf(cmw[0][q], cmw[1][q]), fmaxf(cmw[2][q], cmw[3][q]));
        float osum = 0.f, lsum = 0.f;
        #pragma unroll
        for (int w = 0; w < 4; ++w) {
            float f = __expf(cmw[w][q] - mstar);
            osum = fmaf(f, comb[w][q][h], osum);
            lsum = fmaf(f, clw[w][q], lsum);
        }
        float res = osum / lsum;
        int comp = h >> 6, hh = h & 63;
        out[(size_t)comp * NST + ((size_t)(b*TT + qbase + q)) * HH + hh] = res;
    }
}

extern "C" void kernel_launch(void* const* d_in, const int* in_sizes, int n_in,
                              void* d_out, int out_size, void* d_ws, size_t ws_size,
                              hipStream_t stream)
{
    const float* xr  = (const float*)d_in[0];
    const float* xi  = (const float*)d_in[1];
    const float* Wkr = (const float*)d_in[2];
    const float* Wki = (const float*)d_in[3];
    const float* Wqr = (const float*)d_in[4];
    const float* Wqi = (const float*)d_in[5];
    const float* Wvr = (const float*)d_in[6];
    const float* Wvi = (const float*)d_in[7];

    short* Bt = (short*)d_ws;                               // 1.5 MB
    short* G  = (short*)((char*)d_ws + (2u  << 20));        // 12 MB  [16384][384]
    short* VT = (short*)((char*)d_ws + (16u << 20));        // 4 MB   [2][8][64][2048]
    float* out = (float*)d_out;

    prep_kernel<<<NN, 256, 0, stream>>>(Wkr, Wki, Wqr, Wqi, Wvr, Wvi, Bt);

    dim3 g1(NROW / 128, NN / 128);
    proj_gemm<<<g1, 256, 0, stream>>>(xr, xi, Bt, G);

    dim3 g2(BB, 128);
    vtrans_kernel<<<g2, 256, 0, stream>>>(G, VT);

    dim3 g3(TT / 16, BB);
    attn_kernel<<<g3, 256, 0, stream>>>(G, VT, out);
}